// Round 1
// baseline (96.884 us; speedup 1.0000x reference)
//
#include <hip/hip_runtime.h>
#include <hip/hip_bf16.h>
#include <math.h>

// Problem constants
#define BB 8
#define SS 2048
#define DD 256
#define FF 8
#define NTOK (BB*SS)   // 16384

typedef __bf16 bf16x8 __attribute__((ext_vector_type(8)));
typedef float  f32x4  __attribute__((ext_vector_type(4)));
typedef float  f32x2  __attribute__((ext_vector_type(2)));

// ---------------- Kernel A: h = tanh(x @ W1^T + b1) -> fp8(e4m3) table via MFMA ----------
// R8 structure: ONE block per 64-token group computes ALL 256 output columns, so the
// fp32 x-tile is read from HBM exactly once (16 MB total vs 64 MB in the BN=64 layout;
// the old XCD-swizzle L2 dedup of the 4 n-siblings demonstrably didn't happen: 15us ~ 96MB).
// x -> MFMA A-fragments DIRECTLY in registers (32 VGPR/wave, wn-pair duplication absorbed
// by L1/L2 within the block). The freed LDS holds a double-buffered W chunk
// (64 rows x 256 K bf16 x 2 = 64 KB), one barrier per chunk. XOR swizzle on 16B granules
// (q ^= row&7) makes ds_write/ds_read conflict-free with zero padding.
#define BM 64
#define CH 64           // n-chunk width (W1 rows per LDS tile)
#define NCH (DD/CH)     // 4

__device__ __forceinline__ float fast_tanh(float x) {
    float e = __expf(2.0f * x);
    return 1.0f - 2.0f * __builtin_amdgcn_rcpf(e + 1.0f);
}

__device__ __forceinline__ unsigned pack2_bf16(float a, float b) {
    return (__float_as_uint(a) >> 16) | (__float_as_uint(b) & 0xFFFF0000u);
}

__device__ __forceinline__ unsigned char f32_to_fp8(float v) {
    return (unsigned char)(__builtin_amdgcn_cvt_pk_fp8_f32(v, v, 0, false) & 0xFF);
}

__global__ __launch_bounds__(512, 2) void gemm_tanh_kernel(
    const float* __restrict__ x, const float* __restrict__ W1,
    const float* __restrict__ b1, unsigned char* __restrict__ table)
{
    // 2 x (64 rows x 256 K) bf16 = 65536 B exactly; buffer 0 reused as fp8 scratch.
    __shared__ __align__(16) unsigned short wt[2][CH * DD];

    const int tid  = threadIdx.x;
    const int bx   = blockIdx.x;
    const int tok0 = bx * BM;

    // re-zero padding row 0 (256 fp8 bytes); ws is re-poisoned before every launch
    if (bx == 0 && tid < 64) ((unsigned int*)table)[tid] = 0u;

    const int wave = tid >> 6, lane = tid & 63;
    const int wm = wave >> 1;        // 0..3: 16-row m band
    const int wn = wave & 1;         // 0..1: 32-col n band within each chunk
    const int lr = lane & 15;
    const int kg = lane >> 4;

    // ---- x rows -> A fragments in registers (read once from HBM) ----
    // A-frag layout for 16x16x32: lane(lr,kg) holds row lr, k = c*32 + kg*8 .. +8
    const float* xrow = x + (size_t)(tok0 + wm * 16 + lr) * DD + kg * 8;
    f32x4 xa[8], xb[8];
    #pragma unroll
    for (int c = 0; c < 8; ++c) {
        xa[c] = *(const f32x4*)&xrow[c * 32];
        xb[c] = *(const f32x4*)&xrow[c * 32 + 4];
    }

    // ---- W chunk staging: thread owns 128 contiguous bytes of one W1 row ----
    const int srow = tid >> 3;          // 0..63 (chunk-local W1 row)
    const int scol = (tid & 7) * 32;    // fp32 col base: 0,32,..,224
    f32x4 wr0[8], wrn[8];

    auto wload = [&](int nc, f32x4* wr) {
        const float* wsrc = W1 + (size_t)(nc * CH + srow) * DD + scol;
        #pragma unroll
        for (int j = 0; j < 8; ++j) wr[j] = *(const f32x4*)&wsrc[j * 4];
    };
    auto wstore = [&](int buf, const f32x4* wr) {
        #pragma unroll
        for (int j = 0; j < 4; ++j) {
            uint4 p;
            p.x = pack2_bf16(wr[2*j].x,   wr[2*j].y);
            p.y = pack2_bf16(wr[2*j].z,   wr[2*j].w);
            p.z = pack2_bf16(wr[2*j+1].x, wr[2*j+1].y);
            p.w = pack2_bf16(wr[2*j+1].z, wr[2*j+1].w);
            int q  = (scol >> 3) + j;            // 16B granule index 0..31
            int qp = q ^ (srow & 7);             // XOR swizzle (conflict-free r/w)
            *(uint4*)&wt[buf][srow * DD + qp * 8] = p;
        }
    };

    wload(0, wr0);

    // pack A fragments while W0 is in flight
    bf16x8 af[8];
    #pragma unroll
    for (int c = 0; c < 8; ++c) {
        uint4 p;
        p.x = pack2_bf16(xa[c].x, xa[c].y);
        p.y = pack2_bf16(xa[c].z, xa[c].w);
        p.z = pack2_bf16(xb[c].x, xb[c].y);
        p.w = pack2_bf16(xb[c].z, xb[c].w);
        af[c] = *(bf16x8*)&p;
    }

    wstore(0, wr0);
    __syncthreads();

    f32x4 acc[NCH][2];
    #pragma unroll
    for (int nc = 0; nc < NCH; ++nc)
        #pragma unroll
        for (int nf = 0; nf < 2; ++nf)
            acc[nc][nf] = (f32x4){0.f, 0.f, 0.f, 0.f};

    const int nl0 = wn * 32 + lr;       // chunk-local B row, nf=0
    const int nl1 = nl0 + 16;           // nf=1  (nl1&7 == nl0&7 == lr&7)
    const int sw  = lr & 7;

    #pragma unroll
    for (int nc = 0; nc < NCH; ++nc) {
        const int buf = nc & 1;
        if (nc + 1 < NCH) wload(nc + 1, wrn);   // next chunk's globals in flight early

        #pragma unroll
        for (int c = 0; c < 8; ++c) {
            int q  = c * 4 + kg;
            int qp = q ^ sw;
            bf16x8 bf0 = *(const bf16x8*)&wt[buf][nl0 * DD + qp * 8];
            bf16x8 bf1 = *(const bf16x8*)&wt[buf][nl1 * DD + qp * 8];
            acc[nc][0] = __builtin_amdgcn_mfma_f32_16x16x32_bf16(af[c], bf0, acc[nc][0], 0, 0, 0);
            acc[nc][1] = __builtin_amdgcn_mfma_f32_16x16x32_bf16(af[c], bf1, acc[nc][1], 0, 0, 0);
        }

        if (nc + 1 < NCH) {
            wstore(buf ^ 1, wrn);   // buf^1 reads drained at previous barrier
            __syncthreads();        // one barrier per chunk
        }
    }

    // ---- epilogue: bias + tanh -> fp8, LDS transpose, coalesced uint4 stores ----
    float bj[NCH][2];
    #pragma unroll
    for (int nc = 0; nc < NCH; ++nc) {
        bj[nc][0] = b1[nc * CH + wn * 32 + lr];
        bj[nc][1] = b1[nc * CH + wn * 32 + 16 + lr];
    }

    // chunk 3 reads only wt[1]; wt[0] is free as scratch -> no barrier needed before writes
    unsigned char* sc = (unsigned char*)&wt[0][0];   // [64][272] fp8 scratch (17.4 KB)
    #pragma unroll
    for (int nc = 0; nc < NCH; ++nc) {
        #pragma unroll
        for (int nf = 0; nf < 2; ++nf) {
            #pragma unroll
            for (int r = 0; r < 4; ++r) {
                int row = wm * 16 + kg * 4 + r;      // C/D layout: col=lane&15, row=kg*4+reg
                int col = nc * CH + wn * 32 + nf * 16 + lr;
                float v = fast_tanh(acc[nc][nf][r] + bj[nc][nf]);
                sc[row * 272 + col] = f32_to_fp8(v);
            }
        }
    }
    __syncthreads();
    {
        int row = tid >> 3;                          // 64 rows x 256 B, 32 B per thread
        int off = (tid & 7) * 32;
        uint4 v0 = *(const uint4*)&sc[row * 272 + off];
        uint4 v1 = *(const uint4*)&sc[row * 272 + off + 16];
        *(uint4*)&table[(size_t)(1 + tok0 + row) * DD + off]      = v0;
        *(uint4*)&table[(size_t)(1 + tok0 + row) * DD + off + 16] = v1;
    }
}

// ---------------- Kernel B: fp8 gather + max over F + dot(w2) + bias + mask ----------------
// One wave per token. Halves of the wave take alternating f-rows; uint2 (8 fp8) per lane.
// (Unchanged since round 3.)
__global__ __launch_bounds__(256) void gather_score_kernel(
    const unsigned char* __restrict__ table,
    const int* __restrict__ select_idx,
    const int* __restrict__ word_mask,
    const float* __restrict__ w2,
    const float* __restrict__ b2,
    float* __restrict__ out)
{
    const int tid  = threadIdx.x;
    const int lane = tid & 63;
    const int wv   = tid >> 6;
    const int i    = blockIdx.x * 4 + wv;    // token
    const int half = lane >> 5;
    const int c    = lane & 31;
    const int d0   = c * 8;                  // 8 dims (8 B) per lane

    const int4* sp = (const int4*)(select_idx + (size_t)i * FF);
    int4 q0 = sp[0], q1 = sp[1];
    int rows[4];
    rows[0] = half ? q0.y : q0.x;
    rows[1] = half ? q0.w : q0.z;
    rows[2] = half ? q1.y : q1.x;
    rows[3] = half ? q1.w : q1.z;

    float m[8];
    #pragma unroll
    for (int j = 0; j < 8; ++j) m[j] = -INFINITY;

    #pragma unroll
    for (int it = 0; it < 4; ++it) {
        uint2 u = *(const uint2*)(table + (size_t)rows[it] * DD + d0);
        f32x2 a0 = __builtin_amdgcn_cvt_pk_f32_fp8(u.x, false);
        f32x2 a1 = __builtin_amdgcn_cvt_pk_f32_fp8(u.x, true);
        f32x2 a2 = __builtin_amdgcn_cvt_pk_f32_fp8(u.y, false);
        f32x2 a3 = __builtin_amdgcn_cvt_pk_f32_fp8(u.y, true);
        m[0] = fmaxf(m[0], a0.x); m[1] = fmaxf(m[1], a0.y);
        m[2] = fmaxf(m[2], a1.x); m[3] = fmaxf(m[3], a1.y);
        m[4] = fmaxf(m[4], a2.x); m[5] = fmaxf(m[5], a2.y);
        m[6] = fmaxf(m[6], a3.x); m[7] = fmaxf(m[7], a3.y);
    }

    #pragma unroll
    for (int j = 0; j < 8; ++j) m[j] = fmaxf(m[j], __shfl_xor(m[j], 32));

    f32x4 wa = *(const f32x4*)&w2[d0];
    f32x4 wb = *(const f32x4*)&w2[d0 + 4];
    float p = m[0] * wa.x + m[1] * wa.y + m[2] * wa.z + m[3] * wa.w
            + m[4] * wb.x + m[5] * wb.y + m[6] * wb.z + m[7] * wb.w;

    #pragma unroll
    for (int off = 16; off; off >>= 1) p += __shfl_xor(p, off);

    if (lane == 0) {
        float neg = word_mask[i] ? 0.f : -10000.f;
        out[i] = p + b2[0] + neg;
    }
}

extern "C" void kernel_launch(void* const* d_in, const int* in_sizes, int n_in,
                              void* d_out, int out_size, void* d_ws, size_t ws_size,
                              hipStream_t stream) {
    const float* hs    = (const float*)d_in[0];   // [B,S,D] f32
    const int*   sidx  = (const int*)  d_in[1];   // [B,S,F] i32
    const int*   wmask = (const int*)  d_in[2];   // [B,S]   i32
    const float* W1    = (const float*)d_in[3];   // [D,D]   f32
    const float* b1    = (const float*)d_in[4];   // [D]     f32
    const float* w2    = (const float*)d_in[5];   // [D]     f32
    const float* b2    = (const float*)d_in[6];   // [1]     f32
    float* out = (float*)d_out;                   // [B,S]   f32

    unsigned char* table = (unsigned char*)d_ws;  // [1+NTOK, D] fp8 e4m3 (~4.2 MB)

    gemm_tanh_kernel<<<NTOK / BM, 512, 0, stream>>>(hs, W1, b1, table);
    gather_score_kernel<<<NTOK / 4, 256, 0, stream>>>(table, sidx, wmask, w2, b2, out);
}

// Round 3
// 90.457 us; speedup vs baseline: 1.0711x; 1.0711x over previous
//
#include <hip/hip_runtime.h>
#include <hip/hip_bf16.h>
#include <math.h>

// Problem constants
#define BB 8
#define SS 2048
#define DD 256
#define FF 8
#define NTOK (BB*SS)   // 16384

typedef __bf16 bf16x8 __attribute__((ext_vector_type(8)));
typedef float  f32x4  __attribute__((ext_vector_type(4)));
typedef float  f32x2  __attribute__((ext_vector_type(2)));

// ---------------- Kernel W2B: W1 f32 -> bf16 (once, ~384 KB traffic) ----------------
// Lets the GEMM load B-fragments directly from L2-hot bf16 W1 with single dwordx4 loads,
// removing all W LDS staging / double-buffer barriers from kernel A.
__device__ __forceinline__ unsigned pack2_bf16(float a, float b) {
    return (__float_as_uint(a) >> 16) | (__float_as_uint(b) & 0xFFFF0000u);
}

__global__ __launch_bounds__(256) void w1_to_bf16_kernel(
    const float* __restrict__ W1, unsigned short* __restrict__ W1b)
{
    int i = blockIdx.x * 256 + threadIdx.x;       // 8192 threads x 8 floats
    f32x4 a = *(const f32x4*)&W1[(size_t)i * 8];
    f32x4 b = *(const f32x4*)&W1[(size_t)i * 8 + 4];
    uint4 p;
    p.x = pack2_bf16(a.x, a.y); p.y = pack2_bf16(a.z, a.w);
    p.z = pack2_bf16(b.x, b.y); p.w = pack2_bf16(b.z, b.w);
    *(uint4*)&W1b[(size_t)i * 8] = p;
}

// ---------------- Kernel A: h = tanh(x @ W1^T + b1) -> fp8(e4m3) table via MFMA ----------
// R10 = R9 with the staging-index bug fixed (R9 crashed: slot decode used 16 slots/row
// from the old layout; a 32x256-f32 tile has 64 f32x4 slots/row -> LDS OOB writes).
// Structure: BM=32 tokens/block, ALL 256 cols per block -> x read from HBM exactly once
// (16 MB vs 64 MB in the R4 BN=64 layout). grid 512 x 512thr = 2 blocks/CU, 4 waves/SIMD.
// x: coalesced f32x4 -> bf16 -> XOR-swizzled LDS (16 KB) -> conflict-free ds_read_b128.
// W: B-frags loaded straight from bf16 W1b in global (L2-hot, 128 KB/block, dense
// 16-rows-x-64B per instruction). No W LDS, no mid-loop barriers: per wave the K-loop
// is 16 ds_read + 16 global loads + 32 MFMA, fully compiler-pipelined.
#define BM 32

__device__ __forceinline__ float fast_tanh(float x) {
    float e = __expf(2.0f * x);
    return 1.0f - 2.0f * __builtin_amdgcn_rcpf(e + 1.0f);
}

__device__ __forceinline__ unsigned char f32_to_fp8(float v) {
    return (unsigned char)(__builtin_amdgcn_cvt_pk_fp8_f32(v, v, 0, false) & 0xFF);
}

__global__ __launch_bounds__(512, 4) void gemm_tanh_kernel(
    const float* __restrict__ x, const unsigned short* __restrict__ W1b,
    const float* __restrict__ b1, unsigned char* __restrict__ table)
{
    // x tile 32 x 256 bf16 = 16 KB; reused as fp8 scratch [32][272] in the epilogue
    __shared__ __align__(16) unsigned short xs[BM * DD];

    const int tid  = threadIdx.x;
    const int bx   = blockIdx.x;
    const int tok0 = bx * BM;

    // re-zero padding row 0 (256 fp8 bytes); ws is re-poisoned before every launch
    if (bx == 0 && tid < 64) ((unsigned int*)table)[tid] = 0u;

    const int wave = tid >> 6, lane = tid & 63;
    const int n0 = wave * 32;        // 8 waves = 8 n-bands of 32 cols; each wave does all 32 rows
    const int lr = lane & 15;
    const int kg = lane >> 4;

    // ---- stage x: 32 rows x 256 f32 = 2048 f32x4 slots (64 per row), coalesced,
    //      bf16-packed, XOR-swizzled 16B granules ----
    #pragma unroll
    for (int p = 0; p < 4; ++p) {
        int s = p * 512 + tid;
        int row = s >> 6, k4 = s & 63;             // 64 f32x4 slots per row
        f32x4 v = *(const f32x4*)&x[(size_t)(tok0 + row) * DD + k4 * 4];
        uint2 pk;
        pk.x = pack2_bf16(v.x, v.y);
        pk.y = pack2_bf16(v.z, v.w);
        int g  = k4 >> 1;                          // 16B granule 0..31 within row
        int gp = g ^ (row & 7);                    // swizzle: conflict-free b128 frag reads
        *(uint2*)&xs[row * DD + gp * 8 + (k4 & 1) * 4] = pk;
    }
    __syncthreads();

    f32x4 acc[2][2];
    #pragma unroll
    for (int mf = 0; mf < 2; ++mf)
        #pragma unroll
        for (int nf = 0; nf < 2; ++nf)
            acc[mf][nf] = (f32x4){0.f, 0.f, 0.f, 0.f};

    const unsigned short* wrow0 = W1b + (size_t)(n0 + lr) * DD + kg * 8;       // nf=0
    const unsigned short* wrow1 = W1b + (size_t)(n0 + 16 + lr) * DD + kg * 8;  // nf=1
    const int sw = lr & 7;                         // (row&7) same for row lr and lr+16

    #pragma unroll
    for (int c = 0; c < 8; ++c) {
        int g   = c * 4 + kg;
        int gp8 = (g ^ sw) * 8;
        bf16x8 af0 = *(const bf16x8*)&xs[lr * DD + gp8];           // rows 0..15
        bf16x8 af1 = *(const bf16x8*)&xs[(16 + lr) * DD + gp8];    // rows 16..31
        bf16x8 bf0 = *(const bf16x8*)&wrow0[c * 32];
        bf16x8 bf1 = *(const bf16x8*)&wrow1[c * 32];
        acc[0][0] = __builtin_amdgcn_mfma_f32_16x16x32_bf16(af0, bf0, acc[0][0], 0, 0, 0);
        acc[0][1] = __builtin_amdgcn_mfma_f32_16x16x32_bf16(af0, bf1, acc[0][1], 0, 0, 0);
        acc[1][0] = __builtin_amdgcn_mfma_f32_16x16x32_bf16(af1, bf0, acc[1][0], 0, 0, 0);
        acc[1][1] = __builtin_amdgcn_mfma_f32_16x16x32_bf16(af1, bf1, acc[1][1], 0, 0, 0);
    }

    // ---- epilogue: bias + tanh -> fp8, LDS transpose, coalesced uint4 stores ----
    float bj0 = b1[n0 + lr];
    float bj1 = b1[n0 + 16 + lr];

    __syncthreads();                               // all af reads done: reuse xs as scratch
    unsigned char* sc = (unsigned char*)&xs[0];    // [32][272] fp8 scratch (8.5 KB)
    #pragma unroll
    for (int mf = 0; mf < 2; ++mf) {
        #pragma unroll
        for (int nf = 0; nf < 2; ++nf) {
            #pragma unroll
            for (int r = 0; r < 4; ++r) {
                int row = mf * 16 + kg * 4 + r;    // C/D layout: col=lane&15, row=kg*4+reg
                int col = n0 + nf * 16 + lr;
                float v = fast_tanh(acc[mf][nf][r] + (nf ? bj1 : bj0));
                sc[row * 272 + col] = f32_to_fp8(v);
            }
        }
    }
    __syncthreads();
    {
        int row = tid >> 4;                        // 32 rows x 256 B, 16 B per thread
        int off = (tid & 15) * 16;
        uint4 v = *(const uint4*)&sc[row * 272 + off];
        *(uint4*)&table[(size_t)(1 + tok0 + row) * DD + off] = v;
    }
}

// ---------------- Kernel B: fp8 gather + max over F + dot(w2) + bias + mask ----------------
// One wave per token. Halves of the wave take alternating f-rows; uint2 (8 fp8) per lane.
// (Unchanged since round 3.)
__global__ __launch_bounds__(256) void gather_score_kernel(
    const unsigned char* __restrict__ table,
    const int* __restrict__ select_idx,
    const int* __restrict__ word_mask,
    const float* __restrict__ w2,
    const float* __restrict__ b2,
    float* __restrict__ out)
{
    const int tid  = threadIdx.x;
    const int lane = tid & 63;
    const int wv   = tid >> 6;
    const int i    = blockIdx.x * 4 + wv;    // token
    const int half = lane >> 5;
    const int c    = lane & 31;
    const int d0   = c * 8;                  // 8 dims (8 B) per lane

    const int4* sp = (const int4*)(select_idx + (size_t)i * FF);
    int4 q0 = sp[0], q1 = sp[1];
    int rows[4];
    rows[0] = half ? q0.y : q0.x;
    rows[1] = half ? q0.w : q0.z;
    rows[2] = half ? q1.y : q1.x;
    rows[3] = half ? q1.w : q1.z;

    float m[8];
    #pragma unroll
    for (int j = 0; j < 8; ++j) m[j] = -INFINITY;

    #pragma unroll
    for (int it = 0; it < 4; ++it) {
        uint2 u = *(const uint2*)(table + (size_t)rows[it] * DD + d0);
        f32x2 a0 = __builtin_amdgcn_cvt_pk_f32_fp8(u.x, false);
        f32x2 a1 = __builtin_amdgcn_cvt_pk_f32_fp8(u.x, true);
        f32x2 a2 = __builtin_amdgcn_cvt_pk_f32_fp8(u.y, false);
        f32x2 a3 = __builtin_amdgcn_cvt_pk_f32_fp8(u.y, true);
        m[0] = fmaxf(m[0], a0.x); m[1] = fmaxf(m[1], a0.y);
        m[2] = fmaxf(m[2], a1.x); m[3] = fmaxf(m[3], a1.y);
        m[4] = fmaxf(m[4], a2.x); m[5] = fmaxf(m[5], a2.y);
        m[6] = fmaxf(m[6], a3.x); m[7] = fmaxf(m[7], a3.y);
    }

    #pragma unroll
    for (int j = 0; j < 8; ++j) m[j] = fmaxf(m[j], __shfl_xor(m[j], 32));

    f32x4 wa = *(const f32x4*)&w2[d0];
    f32x4 wb = *(const f32x4*)&w2[d0 + 4];
    float p = m[0] * wa.x + m[1] * wa.y + m[2] * wa.z + m[3] * wa.w
            + m[4] * wb.x + m[5] * wb.y + m[6] * wb.z + m[7] * wb.w;

    #pragma unroll
    for (int off = 16; off; off >>= 1) p += __shfl_xor(p, off);

    if (lane == 0) {
        float neg = word_mask[i] ? 0.f : -10000.f;
        out[i] = p + b2[0] + neg;
    }
}

extern "C" void kernel_launch(void* const* d_in, const int* in_sizes, int n_in,
                              void* d_out, int out_size, void* d_ws, size_t ws_size,
                              hipStream_t stream) {
    const float* hs    = (const float*)d_in[0];   // [B,S,D] f32
    const int*   sidx  = (const int*)  d_in[1];   // [B,S,F] i32
    const int*   wmask = (const int*)  d_in[2];   // [B,S]   i32
    const float* W1    = (const float*)d_in[3];   // [D,D]   f32
    const float* b1    = (const float*)d_in[4];   // [D]     f32
    const float* w2    = (const float*)d_in[5];   // [D]     f32
    const float* b2    = (const float*)d_in[6];   // [1]     f32
    float* out = (float*)d_out;                   // [B,S]   f32

    unsigned char*  table = (unsigned char*)d_ws;               // [1+NTOK, D] fp8 (~4.2 MB)
    unsigned short* W1b   = (unsigned short*)((char*)d_ws + (8u << 20)); // [D,D] bf16 (128 KB)

    w1_to_bf16_kernel<<<32, 256, 0, stream>>>(W1, W1b);
    gemm_tanh_kernel<<<NTOK / BM, 512, 0, stream>>>(hs, W1b, b1, table);
    gather_score_kernel<<<NTOK / 4, 256, 0, stream>>>(table, sidx, wmask, w2, b2, out);
}